// Round 10
// baseline (58.039 us; speedup 1.0000x reference)
//
#include <hip/hip_runtime.h>

#define NB 8
#define C_IN 64
#define HW 65536      // 256*256
#define CF 256
#define FHW 4096      // 64*64
#define NSEG 256
#define FBLK 16       // featsum blocks per batch
#define MBLK 64       // input blocks per batch
#define TOTB 80
#define KBLK 16       // kB blocks per batch
#define MAGIC 0x13579BDFu
#define AG __HIP_MEMORY_SCOPE_AGENT

// ws layout (floats):
// fsum    [NB][FHW]            @ 0       (32768)
// seg_part[NB][MBLK][2][NSEG]  @ 32768   (262144)   0=xsum,1=cnt
// sfg     [NB][NSEG]           @ 294912  (2048)     global binf accumulator
// u32: cnt[NB], ppbits[NB], bflags[NB] @ 296960

// ---------- k1: featsum strips + input stream/histogram (640 blocks) ----------
__global__ __launch_bounds__(256) void k1(
    const float* __restrict__ input, const int* __restrict__ sp,
    const float* __restrict__ feat,
    float* __restrict__ fsum, float* __restrict__ seg_part,
    float* __restrict__ sfg, unsigned* __restrict__ cnt) {
  __shared__ float smem[1024];
  int b = blockIdx.y, e = blockIdx.x, t = threadIdx.x;

  if (e < FBLK) {
    if (e == 0) {          // zero next-stage accumulators (visible at dispatch boundary)
      sfg[b * NSEG + t] = 0.f;
      if (t == 0) cnt[b] = 0u;
    }
    // featsum strip: 256 px (64 float4 cols), all 256 channels, fully reduced
    int q = t & 63, cg = t >> 6;
    const float4* f4 = (const float4*)(feat + (size_t)b * CF * FHW);
    int col = e * 64 + q;
    float4 s = make_float4(0.f, 0.f, 0.f, 0.f);
#pragma unroll 8
    for (int c = cg; c < CF; c += 4) {
      float4 v = f4[(size_t)c * (FHW / 4) + col];
      s.x += v.x; s.y += v.y; s.z += v.z; s.w += v.w;
    }
    float4* lred = (float4*)smem;                  // [4][64] float4
    lred[cg * 64 + q] = s;
    __syncthreads();
    if (t < 64) {
      float4 a = lred[t], b1 = lred[64 + t], c1 = lred[128 + t], d = lred[192 + t];
      a.x += b1.x + c1.x + d.x; a.y += b1.y + c1.y + d.y;
      a.z += b1.z + c1.z + d.z; a.w += b1.w + c1.w + d.w;
      ((float4*)fsum)[(size_t)b * (FHW / 4) + e * 64 + t] = a;
    }
    return;
  }

  // input block: channel-sum + count histogram per segment
  int blk = e - FBLK;
  float* bin_x = smem;
  float* bin_c = smem + NSEG;
  bin_x[t] = 0.f; bin_c[t] = 0.f;
  __syncthreads();
  int v0 = blk * 256 + t;
  const float4* in4 = (const float4*)(input + (size_t)b * C_IN * HW);
  float4 xs = make_float4(0.f, 0.f, 0.f, 0.f);
#pragma unroll
  for (int c = 0; c < C_IN; ++c) {
    float4 v = in4[(size_t)c * (HW / 4) + v0];
    xs.x += v.x; xs.y += v.y; xs.z += v.z; xs.w += v.w;
  }
  int4 sv = ((const int4*)(sp + (size_t)b * HW))[v0];
  atomicAdd(&bin_x[sv.x], xs.x); atomicAdd(&bin_c[sv.x], 1.f);
  atomicAdd(&bin_x[sv.y], xs.y); atomicAdd(&bin_c[sv.y], 1.f);
  atomicAdd(&bin_x[sv.z], xs.z); atomicAdd(&bin_c[sv.z], 1.f);
  atomicAdd(&bin_x[sv.w], xs.w); atomicAdd(&bin_c[sv.w], 1.f);
  __syncthreads();
  float* sb = seg_part + (size_t)(b * MBLK + blk) * 2 * NSEG;
  sb[t] = bin_x[t];
  sb[NSEG + t] = bin_c[t];
}

// ---------- kB: bilinear + last-block-per-batch finisher (128 blocks) ----------
__global__ __launch_bounds__(1024) void kB(
    const int* __restrict__ sp, const float* __restrict__ fsum,
    const float* __restrict__ seg_part, float* __restrict__ sfg,
    unsigned* __restrict__ cnt, unsigned* __restrict__ ppbits,
    unsigned* __restrict__ bflags, float* __restrict__ out) {
  __shared__ float smem[FHW];          // fls, later s2/m1/m2/red
  __shared__ float binf[NSEG];
  __shared__ unsigned lastflag;
  int b = blockIdx.y, chunk = blockIdx.x, t = threadIdx.x;

  ((float4*)smem)[t] = ((const float4*)(fsum + (size_t)b * FHW))[t];
  if (t < NSEG) binf[t] = 0.f;
  __syncthreads();

  int v4 = chunk * 1024 + t;
  int4 sv = ((const int4*)(sp + (size_t)b * HW))[v4];
  int p0 = v4 * 4;
  int y = p0 >> 8;
  float cy = (float)y * (63.0f / 255.0f);
  int iy = (int)cy; float ty = cy - (float)iy; int iy1 = min(iy + 1, 63);
  int svv[4] = {sv.x, sv.y, sv.z, sv.w};
#pragma unroll
  for (int kk = 0; kk < 4; ++kk) {
    int x = (p0 + kk) & 255;
    float cx = (float)x * (63.0f / 255.0f);
    int ix = (int)cx; float tx = cx - (float)ix; int ix1 = min(ix + 1, 63);
    float f00 = smem[iy * 64 + ix],  f10 = smem[iy1 * 64 + ix];
    float f01 = smem[iy * 64 + ix1], f11 = smem[iy1 * 64 + ix1];
    float a0 = f00 * (1.f - ty) + f10 * ty;
    float a1 = f01 * (1.f - ty) + f11 * ty;
    atomicAdd(&binf[svv[kk]], a0 * (1.f - tx) + a1 * tx);
  }
  __syncthreads();
  if (t < NSEG) atomicAdd(&sfg[b * NSEG + t], binf[t]);
  __syncthreads();
  if (t == 0) {
    unsigned old = __hip_atomic_fetch_add(&cnt[b], 1u, __ATOMIC_ACQ_REL, AG);
    lastflag = (old == KBLK - 1) ? 1u : 0u;
  }
  __syncthreads();
  if (!lastflag) return;

  // ---------- finisher for batch b ----------
  __builtin_amdgcn_fence(__ATOMIC_ACQUIRE, "agent");
  float* s2 = smem;            // 512
  float* m1 = smem + 512;      // 256
  float* m2 = smem + 768;      // 256
  float* red = smem + 1024;    // 16
  if (t < 2 * NSEG) {
    const float* base = seg_part + (size_t)b * MBLK * 2 * NSEG + t;
    float s = 0.f;
#pragma unroll
    for (int k = 0; k < MBLK; ++k) s += base[k * 2 * NSEG];
    s2[t] = s;
  }
  __syncthreads();
  if (t < NSEG) {
    float c = s2[NSEG + t];
    m1[t] = s2[t] / (c * 64.0f);
    m2[t] = sfg[b * NSEG + t] / (c * 256.0f);
  }
  __syncthreads();
  int i = t & 255, j0 = (t >> 8) * 64;
  float a1 = m1[i], a2 = m2[i], acc = 0.f;
#pragma unroll
  for (int jj = 0; jj < 64; ++jj) {
    int j = j0 + jj;
    acc += fabsf(fabsf(a1 - m1[j]) - fabsf(a2 - m2[j]));
  }
#pragma unroll
  for (int off = 32; off; off >>= 1) acc += __shfl_down(acc, off);
  if ((t & 63) == 0) red[t >> 6] = acc;
  __syncthreads();
  if (t == 0) {
    float s = 0.f;
#pragma unroll
    for (int w = 0; w < 16; ++w) s += red[w];
    __hip_atomic_store(&ppbits[b], __float_as_uint(s), __ATOMIC_RELAXED, AG);
    __hip_atomic_store(&bflags[b], MAGIC, __ATOMIC_RELEASE, AG);
    if (b == 0) {
      float tot = s;
      for (int ob = 1; ob < NB; ++ob) {
        while (__hip_atomic_load(&bflags[ob], __ATOMIC_ACQUIRE, AG) != MAGIC)
          __builtin_amdgcn_s_sleep(2);
        tot += __uint_as_float(__hip_atomic_load(
            &ppbits[ob], __ATOMIC_RELAXED, AG));
        __hip_atomic_store(&bflags[ob], 0u, __ATOMIC_RELAXED, AG);
      }
      out[0] = tot / 524288.0f;  // NB * NSEG * NSEG
      __hip_atomic_store(&bflags[0], 0u, __ATOMIC_RELAXED, AG);
    }
  }
}

extern "C" void kernel_launch(void* const* d_in, const int* in_sizes, int n_in,
                              void* d_out, int out_size, void* d_ws, size_t ws_size,
                              hipStream_t stream) {
  const float* input   = (const float*)d_in[0];
  const float* feature = (const float*)d_in[1];
  const int*   sp      = (const int*)d_in[2];
  float* ws = (float*)d_ws;
  float*    fsum     = ws;
  float*    seg_part = ws + (size_t)NB * FHW;
  float*    sfg      = seg_part + (size_t)NB * MBLK * 2 * NSEG;
  unsigned* cnt      = (unsigned*)(sfg + (size_t)NB * NSEG);
  unsigned* ppbits   = cnt + NB;
  unsigned* bflags   = ppbits + NB;

  k1<<<dim3(TOTB, NB), 256, 0, stream>>>(input, sp, feature, fsum, seg_part,
                                         sfg, cnt);
  kB<<<dim3(KBLK, NB), 1024, 0, stream>>>(sp, fsum, seg_part, sfg, cnt,
                                          ppbits, bflags, (float*)d_out);
}

// Round 11
// 48.260 us; speedup vs baseline: 1.2026x; 1.2026x over previous
//
#include <hip/hip_runtime.h>

#define NB 8
#define C_IN 64
#define HW 65536      // 256*256
#define CF 256
#define FHW 4096      // 64*64
#define NSEG 256
#define FBLK 16       // featsum+bilinear blocks per batch
#define MBLK 64       // input blocks per batch
#define TOTB 80
#define MAGIC 0x13579BDFu
#define AG __HIP_MEMORY_SCOPE_AGENT

// ws layout (floats):
// seg_part [NB][MBLK][2][NSEG]  @ 0       (262144)   0=xsum,1=cnt
// binf_part[NB][FBLK][NSEG]     @ 262144  (32768)
// u32: ppbits[NB], bflags[NB]   @ 294912

// ---------- k1: input stream/histogram + featsum-strip+bilinear (640 blocks) ----------
__global__ __launch_bounds__(256) void k1(
    const float* __restrict__ input, const int* __restrict__ sp,
    const float* __restrict__ feat,
    float* __restrict__ seg_part, float* __restrict__ binf_part) {
  __shared__ float smem[1600];   // [0,1024): lred ; [1024,1344): fls[5][64] ; [1344,1600): binf
  int b = blockIdx.y, e = blockIdx.x, t = threadIdx.x;

  if (e < FBLK) {
    float* fls  = smem + 1024;
    float* binf = smem + 1344;
    binf[t] = 0.f;
    const float4* f4 = (const float4*)(feat + (size_t)b * CF * FHW);

    // pass A: native rows 4e..4e+3 (64 float4 cols), 4 chgroups x 64 channels
    {
      int q = t & 63, cg = t >> 6;
      int col = e * 64 + q;
      float4 s = make_float4(0.f, 0.f, 0.f, 0.f);
#pragma unroll 8
      for (int c = cg; c < CF; c += 4) {
        float4 v = f4[(size_t)c * (FHW / 4) + col];
        s.x += v.x; s.y += v.y; s.z += v.z; s.w += v.w;
      }
      float4* lred = (float4*)smem;                  // [4][64] float4
      lred[cg * 64 + q] = s;
      __syncthreads();
      if (t < 64) {
        float4 a = lred[t], b1 = lred[64 + t], c1 = lred[128 + t], d = lred[192 + t];
        a.x += b1.x + c1.x + d.x; a.y += b1.y + c1.y + d.y;
        a.z += b1.z + c1.z + d.z; a.w += b1.w + c1.w + d.w;
        ((float4*)fls)[t] = a;                       // fls rows 0..3
      }
      __syncthreads();
    }
    // pass B: overlap row 4e+4 (16 float4 cols), 16 chgroups x 16 channels
    if (e < FBLK - 1) {
      int c2 = t & 15, cg2 = t >> 4;
      int col = (4 * e + 4) * 16 + c2;
      float4 s = make_float4(0.f, 0.f, 0.f, 0.f);
#pragma unroll
      for (int k = 0; k < 16; ++k) {
        float4 v = f4[(size_t)(cg2 * 16 + k) * (FHW / 4) + col];
        s.x += v.x; s.y += v.y; s.z += v.z; s.w += v.w;
      }
      float4* lredB = (float4*)smem;                 // [16][16] float4
      lredB[cg2 * 16 + c2] = s;
      __syncthreads();
      if (t < 16) {
        float4 a = lredB[t];
#pragma unroll
        for (int g = 1; g < 16; ++g) {
          float4 v = lredB[g * 16 + t];
          a.x += v.x; a.y += v.y; a.z += v.z; a.w += v.w;
        }
        ((float4*)fls)[64 + t] = a;                  // fls row 4
      }
      __syncthreads();
    }

    // bilinear for output rows y0..y1 (iy in [4e,4e+3]), column x = t
    int y0 = (1020 * e + 62) / 63;
    int y1 = (e == FBLK - 1) ? 255 : (1020 * (e + 1) + 62) / 63 - 1;
    float cx = (float)t * (63.0f / 255.0f);
    int ix = (int)cx; float tx = cx - (float)ix; int ix1 = min(ix + 1, 63);
    const int* sprow = sp + (size_t)b * HW + t;
    for (int y = y0; y <= y1; ++y) {
      int iy = (y * 63) / 255;
      float ty = (float)y * (63.0f / 255.0f) - (float)iy;
      int r = iy - 4 * e;
      int r1 = min(iy + 1, 63) - 4 * e;
      float f00 = fls[r * 64 + ix],  f10 = fls[r1 * 64 + ix];
      float f01 = fls[r * 64 + ix1], f11 = fls[r1 * 64 + ix1];
      float a0 = f00 * (1.f - ty) + f10 * ty;
      float a1 = f01 * (1.f - ty) + f11 * ty;
      int s = sprow[y * 256];
      atomicAdd(&binf[s], a0 * (1.f - tx) + a1 * tx);
    }
    __syncthreads();
    binf_part[(size_t)(b * FBLK + e) * NSEG + t] = binf[t];
    return;
  }

  // input block: channel-sum + count histogram per segment
  int blk = e - FBLK;
  float* bin_x = smem;
  float* bin_c = smem + NSEG;
  bin_x[t] = 0.f; bin_c[t] = 0.f;
  __syncthreads();
  int v0 = blk * 256 + t;
  const float4* in4 = (const float4*)(input + (size_t)b * C_IN * HW);
  float4 xs = make_float4(0.f, 0.f, 0.f, 0.f);
#pragma unroll
  for (int c = 0; c < C_IN; ++c) {
    float4 v = in4[(size_t)c * (HW / 4) + v0];
    xs.x += v.x; xs.y += v.y; xs.z += v.z; xs.w += v.w;
  }
  int4 sv = ((const int4*)(sp + (size_t)b * HW))[v0];
  atomicAdd(&bin_x[sv.x], xs.x); atomicAdd(&bin_c[sv.x], 1.f);
  atomicAdd(&bin_x[sv.y], xs.y); atomicAdd(&bin_c[sv.y], 1.f);
  atomicAdd(&bin_x[sv.z], xs.z); atomicAdd(&bin_c[sv.z], 1.f);
  atomicAdd(&bin_x[sv.w], xs.w); atomicAdd(&bin_c[sv.w], 1.f);
  __syncthreads();
  float* sb = seg_part + (size_t)(b * MBLK + blk) * 2 * NSEG;
  sb[t] = bin_x[t];
  sb[NSEG + t] = bin_c[t];
}

// ---------- k3: reduce partials, means, pair sum, cross-batch finish ----------
__global__ __launch_bounds__(1024) void k3(
    const float* __restrict__ seg_part, const float* __restrict__ binf_part,
    unsigned* __restrict__ ppbits, unsigned* __restrict__ bflags,
    float* __restrict__ out) {
  __shared__ float s2[2 * NSEG];
  __shared__ float sf[NSEG];
  __shared__ float m1[NSEG], m2[NSEG];
  __shared__ float red[16];
  int b = blockIdx.x, t = threadIdx.x;
  if (t < 2 * NSEG) {
    const float* base = seg_part + (size_t)b * MBLK * 2 * NSEG + t;
    float s = 0.f;
#pragma unroll
    for (int k = 0; k < MBLK; ++k) s += base[k * 2 * NSEG];
    s2[t] = s;
  } else if (t < 3 * NSEG) {
    int u = t - 2 * NSEG;
    const float* base = binf_part + (size_t)b * FBLK * NSEG + u;
    float s = 0.f;
#pragma unroll
    for (int k = 0; k < FBLK; ++k) s += base[k * NSEG];
    sf[u] = s;
  }
  __syncthreads();
  if (t < NSEG) {
    float cnt = s2[NSEG + t];
    m1[t] = s2[t] / (cnt * 64.0f);
    m2[t] = sf[t] / (cnt * 256.0f);
  }
  __syncthreads();
  int i = t & 255, j0 = (t >> 8) * 64;
  float a1 = m1[i], a2 = m2[i], acc = 0.f;
#pragma unroll
  for (int jj = 0; jj < 64; ++jj) {
    int j = j0 + jj;
    acc += fabsf(fabsf(a1 - m1[j]) - fabsf(a2 - m2[j]));
  }
#pragma unroll
  for (int off = 32; off; off >>= 1) acc += __shfl_down(acc, off);
  if ((t & 63) == 0) red[t >> 6] = acc;
  __syncthreads();
  if (t == 0) {
    float s = 0.f;
#pragma unroll
    for (int w = 0; w < 16; ++w) s += red[w];
    __hip_atomic_store(&ppbits[b], __float_as_uint(s), __ATOMIC_RELAXED, AG);
    __hip_atomic_store(&bflags[b], MAGIC, __ATOMIC_RELEASE, AG);
    if (b == 0) {
      float tot = s;
      for (int ob = 1; ob < NB; ++ob) {
        while (__hip_atomic_load(&bflags[ob], __ATOMIC_ACQUIRE, AG) != MAGIC)
          __builtin_amdgcn_s_sleep(2);
        tot += __uint_as_float(__hip_atomic_load(
            &ppbits[ob], __ATOMIC_RELAXED, AG));
        __hip_atomic_store(&bflags[ob], 0u, __ATOMIC_RELAXED, AG);
      }
      out[0] = tot / 524288.0f;  // NB * NSEG * NSEG
      __hip_atomic_store(&bflags[0], 0u, __ATOMIC_RELAXED, AG);
    }
  }
}

extern "C" void kernel_launch(void* const* d_in, const int* in_sizes, int n_in,
                              void* d_out, int out_size, void* d_ws, size_t ws_size,
                              hipStream_t stream) {
  const float* input   = (const float*)d_in[0];
  const float* feature = (const float*)d_in[1];
  const int*   sp      = (const int*)d_in[2];
  float* ws = (float*)d_ws;
  float*    seg_part  = ws;
  float*    binf_part = ws + (size_t)NB * MBLK * 2 * NSEG;
  unsigned* ppbits    = (unsigned*)(binf_part + (size_t)NB * FBLK * NSEG);
  unsigned* bflags    = ppbits + NB;

  k1<<<dim3(TOTB, NB), 256, 0, stream>>>(input, sp, feature, seg_part, binf_part);
  k3<<<dim3(NB), 1024, 0, stream>>>(seg_part, binf_part, ppbits, bflags,
                                    (float*)d_out);
}

// Round 12
// 46.637 us; speedup vs baseline: 1.2445x; 1.0348x over previous
//
#include <hip/hip_runtime.h>

#define NB 8
#define C_IN 64
#define HW 65536      // 256*256
#define CF 256
#define FHW 4096      // 64*64
#define NSEG 256
#define FBLK 16       // featsum blocks per batch
#define MBLK 64       // input blocks per batch
#define TOTB 80
#define MAGIC 0x13579BDFu
#define AG __HIP_MEMORY_SCOPE_AGENT

// ws layout (floats):
// fsum     [NB][FHW]            @ 0       (32768)
// seg_part [NB][MBLK][2][NSEG]  @ 32768   (262144)   0=xsum,1=cnt
// binf_part[NB][MBLK][NSEG]     @ 294912  (131072)
// u32: ppbits[NB], bflags[NB]   @ 425984

// ---------- k1: featsum strips + input stream/histogram (640 blocks) ----------
__global__ __launch_bounds__(256) void k1(
    const float* __restrict__ input, const int* __restrict__ sp,
    const float* __restrict__ feat,
    float* __restrict__ fsum, float* __restrict__ seg_part) {
  __shared__ float smem[1024];
  int b = blockIdx.y, e = blockIdx.x, t = threadIdx.x;

  if (e < FBLK) {
    // featsum strip: 256 px (64 float4 cols), all 256 channels, fully reduced
    int q = t & 63, cg = t >> 6;
    const float4* f4 = (const float4*)(feat + (size_t)b * CF * FHW);
    int col = e * 64 + q;
    float4 s = make_float4(0.f, 0.f, 0.f, 0.f);
#pragma unroll 8
    for (int c = cg; c < CF; c += 4) {
      float4 v = f4[(size_t)c * (FHW / 4) + col];
      s.x += v.x; s.y += v.y; s.z += v.z; s.w += v.w;
    }
    float4* lred = (float4*)smem;                  // [4][64] float4
    lred[cg * 64 + q] = s;
    __syncthreads();
    if (t < 64) {
      float4 a = lred[t], b1 = lred[64 + t], c1 = lred[128 + t], d = lred[192 + t];
      a.x += b1.x + c1.x + d.x; a.y += b1.y + c1.y + d.y;
      a.z += b1.z + c1.z + d.z; a.w += b1.w + c1.w + d.w;
      ((float4*)fsum)[(size_t)b * (FHW / 4) + e * 64 + t] = a;
    }
    return;
  }

  // input block: channel-sum + count histogram per segment
  int blk = e - FBLK;
  float* bin_x = smem;
  float* bin_c = smem + NSEG;
  bin_x[t] = 0.f; bin_c[t] = 0.f;
  __syncthreads();
  int v0 = blk * 256 + t;
  const float4* in4 = (const float4*)(input + (size_t)b * C_IN * HW);
  float4 xs = make_float4(0.f, 0.f, 0.f, 0.f);
#pragma unroll
  for (int c = 0; c < C_IN; ++c) {
    float4 v = in4[(size_t)c * (HW / 4) + v0];
    xs.x += v.x; xs.y += v.y; xs.z += v.z; xs.w += v.w;
  }
  int4 sv = ((const int4*)(sp + (size_t)b * HW))[v0];
  atomicAdd(&bin_x[sv.x], xs.x); atomicAdd(&bin_c[sv.x], 1.f);
  atomicAdd(&bin_x[sv.y], xs.y); atomicAdd(&bin_c[sv.y], 1.f);
  atomicAdd(&bin_x[sv.z], xs.z); atomicAdd(&bin_c[sv.z], 1.f);
  atomicAdd(&bin_x[sv.w], xs.w); atomicAdd(&bin_c[sv.w], 1.f);
  __syncthreads();
  float* sb = seg_part + (size_t)(b * MBLK + blk) * 2 * NSEG;
  sb[t] = bin_x[t];
  sb[NSEG + t] = bin_c[t];
}

// ---------- k2: lightweight bilinear — 4 output rows per block ----------
__global__ __launch_bounds__(256) void k2(
    const int* __restrict__ sp, const float* __restrict__ fsum,
    float* __restrict__ binf_part) {
  __shared__ float fls[192];           // 3 fsum rows of 64
  __shared__ float binf[NSEG];
  int blk = blockIdx.x, b = blockIdx.y, t = threadIdx.x;
  int r0 = (int)((float)(4 * blk) * (63.0f / 255.0f));
  if (t < 48) {
    int j = t >> 4, c4 = t & 15;
    int row = min(r0 + j, 63);
    ((float4*)fls)[t] =
        ((const float4*)(fsum + (size_t)b * FHW))[row * 16 + c4];
  }
  binf[t] = 0.f;
  __syncthreads();
  float cx = (float)t * (63.0f / 255.0f);
  int ix = (int)cx; float tx = cx - (float)ix; int ix1 = min(ix + 1, 63);
  const int* spb = sp + (size_t)b * HW;
#pragma unroll
  for (int j = 0; j < 4; ++j) {
    int y = 4 * blk + j;
    float cy = (float)y * (63.0f / 255.0f);
    int iy = (int)cy; float ty = cy - (float)iy;
    int lr = iy - r0, lr1 = min(iy + 1, 63) - r0;
    float f00 = fls[lr * 64 + ix],  f10 = fls[lr1 * 64 + ix];
    float f01 = fls[lr * 64 + ix1], f11 = fls[lr1 * 64 + ix1];
    float a0 = f00 * (1.f - ty) + f10 * ty;
    float a1 = f01 * (1.f - ty) + f11 * ty;
    int s = spb[y * 256 + t];
    atomicAdd(&binf[s], a0 * (1.f - tx) + a1 * tx);
  }
  __syncthreads();
  binf_part[(size_t)(b * MBLK + blk) * NSEG + t] = binf[t];
}

// ---------- k3: reduce partials, means, pair sum, cross-batch finish ----------
__global__ __launch_bounds__(1024) void k3(
    const float* __restrict__ seg_part, const float* __restrict__ binf_part,
    unsigned* __restrict__ ppbits, unsigned* __restrict__ bflags,
    float* __restrict__ out) {
  __shared__ float s2[2 * NSEG];
  __shared__ float sf[NSEG];
  __shared__ float m1[NSEG], m2[NSEG];
  __shared__ float red[16];
  int b = blockIdx.x, t = threadIdx.x;
  if (t < 2 * NSEG) {
    const float* base = seg_part + (size_t)b * MBLK * 2 * NSEG + t;
    float s = 0.f;
#pragma unroll
    for (int k = 0; k < MBLK; ++k) s += base[k * 2 * NSEG];
    s2[t] = s;
  } else if (t < 3 * NSEG) {
    int u = t - 2 * NSEG;
    const float* base = binf_part + (size_t)b * MBLK * NSEG + u;
    float s = 0.f;
#pragma unroll
    for (int k = 0; k < MBLK; ++k) s += base[k * NSEG];
    sf[u] = s;
  }
  __syncthreads();
  if (t < NSEG) {
    float cnt = s2[NSEG + t];
    m1[t] = s2[t] / (cnt * 64.0f);
    m2[t] = sf[t] / (cnt * 256.0f);
  }
  __syncthreads();
  int i = t & 255, j0 = (t >> 8) * 64;
  float a1 = m1[i], a2 = m2[i], acc = 0.f;
#pragma unroll
  for (int jj = 0; jj < 64; ++jj) {
    int j = j0 + jj;
    acc += fabsf(fabsf(a1 - m1[j]) - fabsf(a2 - m2[j]));
  }
#pragma unroll
  for (int off = 32; off; off >>= 1) acc += __shfl_down(acc, off);
  if ((t & 63) == 0) red[t >> 6] = acc;
  __syncthreads();
  if (t == 0) {
    float s = 0.f;
#pragma unroll
    for (int w = 0; w < 16; ++w) s += red[w];
    __hip_atomic_store(&ppbits[b], __float_as_uint(s), __ATOMIC_RELAXED, AG);
    __hip_atomic_store(&bflags[b], MAGIC, __ATOMIC_RELEASE, AG);
    if (b == 0) {
      float tot = s;
      for (int ob = 1; ob < NB; ++ob) {
        while (__hip_atomic_load(&bflags[ob], __ATOMIC_ACQUIRE, AG) != MAGIC)
          __builtin_amdgcn_s_sleep(2);
        tot += __uint_as_float(__hip_atomic_load(
            &ppbits[ob], __ATOMIC_RELAXED, AG));
        __hip_atomic_store(&bflags[ob], 0u, __ATOMIC_RELAXED, AG);
      }
      out[0] = tot / 524288.0f;  // NB * NSEG * NSEG
      __hip_atomic_store(&bflags[0], 0u, __ATOMIC_RELAXED, AG);
    }
  }
}

extern "C" void kernel_launch(void* const* d_in, const int* in_sizes, int n_in,
                              void* d_out, int out_size, void* d_ws, size_t ws_size,
                              hipStream_t stream) {
  const float* input   = (const float*)d_in[0];
  const float* feature = (const float*)d_in[1];
  const int*   sp      = (const int*)d_in[2];
  float* ws = (float*)d_ws;
  float*    fsum      = ws;
  float*    seg_part  = ws + (size_t)NB * FHW;
  float*    binf_part = seg_part + (size_t)NB * MBLK * 2 * NSEG;
  unsigned* ppbits    = (unsigned*)(binf_part + (size_t)NB * MBLK * NSEG);
  unsigned* bflags    = ppbits + NB;

  k1<<<dim3(TOTB, NB), 256, 0, stream>>>(input, sp, feature, fsum, seg_part);
  k2<<<dim3(MBLK, NB), 256, 0, stream>>>(sp, fsum, binf_part);
  k3<<<dim3(NB), 1024, 0, stream>>>(seg_part, binf_part, ppbits, bflags,
                                    (float*)d_out);
}